// Round 3
// baseline (195.288 us; speedup 1.0000x reference)
//
#include <hip/hip_runtime.h>
#include <math.h>

#define NEXP 18
#define NBEAD 4
#define EPSV 1e-8f
#define ML2 (0.02f * 0.02f)

#define AS1U(p) ((const __attribute__((address_space(1))) unsigned*)(p))
#define AS3U(p) ((__attribute__((address_space(3))) unsigned*)(p))

// LDS: sT 15360 + sP 15360 + sBits 496 + sTbl 1152 = 32368 B -> 5 blocks/CU.
__global__ __launch_bounds__(256, 5) void loss_kernel(
    const float* __restrict__ xin, const float* __restrict__ y_true,
    const float* __restrict__ y_pred, const float* __restrict__ mask,
    const int* __restrict__ trip, const int* __restrict__ valid,
    float* __restrict__ out, int n, float inv_n) {
    __shared__ float sT[3840];       // 256 rows x 15
    __shared__ float sP[3840];
    __shared__ unsigned sBits[124];  // 3840 mask bits, linear layout; reused as red[]
    __shared__ unsigned sTbl[72][4]; // 8 triplets/combo, 2 x 16-bit entries per word
                                     // entry: oi|oj<<4|ok<<8|okflag<<12, o* = atom*3

    const int tid = threadIdx.x;
    const int lane = tid & 63;
    const int wv = tid >> 6;

    if (tid < 124) sBits[tid] = 0u;
    if (tid < NEXP * NBEAD) {
        unsigned w[4] = {0u, 0u, 0u, 0u};
#pragma unroll
        for (int t = 0; t < 8; t++) {
            int b = tid * 8 + t;
            int i = trip[b * 3 + 0], j = trip[b * 3 + 1], k = trip[b * 3 + 2];
            unsigned ok = (i >= 0 && j >= 0 && k >= 0 && valid[b] > 0) ? 1u : 0u;
            unsigned oi = 3u * (unsigned)min(max(i, 0), 4);
            unsigned oj = 3u * (unsigned)min(max(j, 0), 4);
            unsigned ov = 3u * (unsigned)min(max(k, 0), 4);
            unsigned e = oi | (oj << 4) | (ov << 8) | (ok << 12);
            w[t >> 1] |= e << ((t & 1) * 16);
        }
        sTbl[tid][0] = w[0]; sTbl[tid][1] = w[1];
        sTbl[tid][2] = w[2]; sTbl[tid][3] = w[3];
    }
    __syncthreads();

    const int row0 = blockIdx.x * 256;
    int rows = n - row0;
    if (rows > 256) rows = 256;
    const int cnt = rows * 15;
    const int cnt4 = cnt >> 2;
    const size_t base = (size_t)row0 * 15;
    const float4* gt = (const float4*)(y_true + base);
    const float4* gp = (const float4*)(y_pred + base);
    const float4* gm = (const float4*)(mask + base);
    float4* sT4 = (float4*)sT;
    float4* sP4 = (float4*)sP;

    // Async direct-to-LDS staging of T/P: wave-uniform LDS base + lane*16B.
    for (int ib = wv * 64; ib + 64 <= cnt4; ib += 256) {
        __builtin_amdgcn_global_load_lds(AS1U(gt + ib + lane), AS3U(sT4 + ib), 16, 0, 0);
        __builtin_amdgcn_global_load_lds(AS1U(gp + ib + lane), AS3U(sP4 + ib), 16, 0, 0);
    }
    // Tail (last block only): regular path.
    for (int i = (cnt4 & ~63) + tid; i < cnt4; i += 256) { sT4[i] = gt[i]; sP4[i] = gp[i]; }
    for (int i = (cnt4 << 2) + tid; i < cnt; i += 256) {
        sT[i] = y_true[base + i];
        sP[i] = y_pred[base + i];
    }

    // Mask -> bits (overlaps the in-flight direct-to-LDS loads). Div-free.
    for (int i = tid; i < cnt4; i += 256) {
        float4 m4 = gm[i];
        unsigned b0 = (m4.x > 0.f ? 1u : 0u) | (m4.y > 0.f ? 2u : 0u) |
                      (m4.z > 0.f ? 4u : 0u) | (m4.w > 0.f ? 8u : 0u);
        if (b0) {
            int e = i << 2;
            unsigned long long v = (unsigned long long)b0 << (e & 31);
            atomicOr(&sBits[e >> 5], (unsigned)v);
            unsigned hi = (unsigned)(v >> 32);
            if (hi) atomicOr(&sBits[(e >> 5) + 1], hi);
        }
    }
    for (int i = (cnt4 << 2) + tid; i < cnt; i += 256) {
        if (mask[base + i] > 0.f) atomicOr(&sBits[i >> 5], 1u << (i & 31));
    }
    __syncthreads();

    float result = 0.0f;
    const int row = row0 + tid;
    if (row < n) {
        const float* st = sT + tid * 15;  // stride 15 dwords (odd) -> benign banking
        const float* sp = sP + tid * 15;
        const int bb = tid * 15;
        unsigned long long mw =
            ((unsigned long long)sBits[(bb >> 5) + 1] << 32) | sBits[bb >> 5];
        const unsigned mrow = (unsigned)((mw >> (bb & 31)) & 0x7fffu);

        // ---- atom MSE (mask is binary -> bit test is exact) ----
        float num_a = 0.f, den_a = 0.f;
        unsigned avm2 = 0u;  // validity bit at position 3*a (offset-indexed)
#pragma unroll
        for (int a = 0; a < 5; a++) {
            unsigned mb = (mrow >> (3 * a)) & 7u;
            float d0 = st[3 * a + 0] - sp[3 * a + 0];
            float d1 = st[3 * a + 1] - sp[3 * a + 1];
            float d2 = st[3 * a + 2] - sp[3 * a + 2];
            float se = (mb & 1u ? d0 * d0 : 0.f) + (mb & 2u ? d1 * d1 : 0.f) +
                       (mb & 4u ? d2 * d2 : 0.f);
            if (mb) { num_a += se; den_a += 1.f; avm2 |= 1u << (3 * a); }
        }
        result = num_a / (den_a + EPSV);

        // ---- angle part ----
        float2 gb = *(const float2*)(xin + (size_t)row * 38 + 36);
        float beadf = isfinite(gb.x) ? gb.x : 0.f;
        float gatef = isfinite(gb.y) ? gb.y : 0.f;
        gatef = fminf(fmaxf(gatef, -1e6f), 1e6f);
        beadf = fminf(fmaxf(beadf, -1e6f), 1e6f);
        int res_id = min(max((int)rintf(gatef) - 1, 0), NEXP - 1);
        int bead_id = min(max((int)rintf(beadf), 0), NBEAD - 1);
        int combo = res_id * NBEAD + bead_id;
        unsigned tw0 = sTbl[combo][0], tw1 = sTbl[combo][1];
        unsigned tw2 = sTbl[combo][2], tw3 = sTbl[combo][3];

        float num_g = 0.f, den_g = 0.f;
#pragma unroll
        for (int t = 0; t < 8; t++) {
            unsigned wrd = (t < 2) ? tw0 : (t < 4) ? tw1 : (t < 6) ? tw2 : tw3;
            unsigned e = (wrd >> ((t & 1) * 16)) & 0xffffu;
            int oi = e & 15, oj = (e >> 4) & 15, ov = (e >> 8) & 15;
            bool wok = ((e >> 12) & 1u) != 0u;

            // dynamic LDS gathers replace 6 x cndmask-select chains
            float tix = st[oi], tiy = st[oi + 1], tiz = st[oi + 2];
            float tjx = st[oj], tjy = st[oj + 1], tjz = st[oj + 2];
            float tkx = st[ov], tky = st[ov + 1], tkz = st[ov + 2];
            float pix = sp[oi], piy = sp[oi + 1], piz = sp[oi + 2];
            float pjx = sp[oj], pjy = sp[oj + 1], pjz = sp[oj + 2];
            float pkx = sp[ov], pky = sp[ov + 1], pkz = sp[ov + 2];

            float v1tx = tix - tjx, v1ty = tiy - tjy, v1tz = tiz - tjz;
            float v2tx = tkx - tjx, v2ty = tky - tjy, v2tz = tkz - tjz;
            float v1px = pix - pjx, v1py = piy - pjy, v1pz = piz - pjz;
            float v2px = pkx - pjx, v2py = pky - pjy, v2pz = pkz - pjz;

            float l1t = fmaf(v1tx, v1tx, fmaf(v1ty, v1ty, v1tz * v1tz));
            float l2t = fmaf(v2tx, v2tx, fmaf(v2ty, v2ty, v2tz * v2tz));
            float l1p = fmaf(v1px, v1px, fmaf(v1py, v1py, v1pz * v1pz));
            float l2p = fmaf(v2px, v2px, fmaf(v2py, v2py, v2pz * v2pz));

            bool okv = wok && ((avm2 >> oi) & 1) && ((avm2 >> oj) & 1) &&
                       ((avm2 >> ov) & 1) && (l1t > ML2) && (l2t > ML2) &&
                       (l1p > ML2) && (l2p > ML2);

            float rt = __builtin_amdgcn_rsqf(fmaxf(l1t, ML2) * fmaxf(l2t, ML2));
            float rp = __builtin_amdgcn_rsqf(fmaxf(l1p, ML2) * fmaxf(l2p, ML2));

            float dott = fmaf(v1tx, v2tx, fmaf(v1ty, v2ty, v1tz * v2tz));
            float dotp = fmaf(v1px, v2px, fmaf(v1py, v2py, v1pz * v2pz));
            float cut = dott * rt;
            float cup = dotp * rp;
            float cost = fminf(fmaxf(cut, -1.f + 1e-6f), 1.f - 1e-6f);
            float cosp = fminf(fmaxf(cup, -1.f + 1e-6f), 1.f - 1e-6f);
            // |u1 x u2| = sqrt(1 - cos^2) with unclipped cos
            float sint = __builtin_amdgcn_sqrtf(fmaxf(fmaf(-cut, cut, 1.f), 0.f));
            float sinp = __builtin_amdgcn_sqrtf(fmaxf(fmaf(-cup, cup, 1.f), 0.f));

            float dc = cosp - cost, dsn = sinp - sint;
            if (okv) { num_g += fmaf(dc, dc, dsn * dsn); den_g += 1.f; }
        }
        result += num_g / (den_g + EPSV);
    }

    // ---- block reduction (red aliases sBits; barrier protects reuse) ----
    __syncthreads();
#pragma unroll
    for (int off = 32; off > 0; off >>= 1)
        result += __shfl_down(result, off, 64);
    float* red = (float*)sBits;
    if (lane == 0) red[wv] = result;
    __syncthreads();
    if (tid == 0) atomicAdd(out, (red[0] + red[1] + red[2] + red[3]) * inv_n);
}

extern "C" void kernel_launch(void* const* d_in, const int* in_sizes, int n_in,
                              void* d_out, int out_size, void* d_ws, size_t ws_size,
                              hipStream_t stream) {
    const float* x = (const float*)d_in[0];
    const float* y_true = (const float*)d_in[1];
    const float* y_pred = (const float*)d_in[2];
    const float* mask = (const float*)d_in[3];
    const int* trip = (const int*)d_in[4];
    const int* valid = (const int*)d_in[5];
    float* out = (float*)d_out;

    const int n = in_sizes[1] / 15;  // N rows (y_true is N x 15)

    hipMemsetAsync(out, 0, sizeof(float), stream);
    const int blocks = (n + 255) / 256;
    loss_kernel<<<blocks, 256, 0, stream>>>(x, y_true, y_pred, mask, trip, valid, out, n,
                                            1.0f / (float)n);
}

// Round 4
// 191.114 us; speedup vs baseline: 1.0218x; 1.0218x over previous
//
#include <hip/hip_runtime.h>
#include <math.h>

#define NEXP 18
#define NBEAD 4
#define EPSV 1e-8f
#define ML2 (0.02f * 0.02f)

#define AS1U(p) ((const __attribute__((address_space(1))) unsigned*)(p))
#define AS3U(p) ((__attribute__((address_space(3))) unsigned*)(p))

// LDS: sT 15360 + sP 15360 + sBits 496 + sTbl 1152 = 32368 B -> 5 blocks/CU.
__global__ __launch_bounds__(256, 5) void loss_kernel(
    const float* __restrict__ xin, const float* __restrict__ y_true,
    const float* __restrict__ y_pred, const float* __restrict__ mask,
    const int* __restrict__ trip, const int* __restrict__ valid,
    float* __restrict__ partial, int n) {
    __shared__ float sT[3840];       // 256 rows x 15
    __shared__ float sP[3840];
    __shared__ unsigned sBits[124];  // 3840 mask bits, linear layout; reused as red[]
    __shared__ unsigned sTbl[72][4]; // 8 triplets/combo, 2 x 16-bit entries per word
                                     // entry: oi|oj<<4|ok<<8|okflag<<12, o* = atom*3

    const int tid = threadIdx.x;
    const int lane = tid & 63;
    const int wv = tid >> 6;

    if (tid < 124) sBits[tid] = 0u;
    if (tid < NEXP * NBEAD) {
        unsigned w[4] = {0u, 0u, 0u, 0u};
#pragma unroll
        for (int t = 0; t < 8; t++) {
            int b = tid * 8 + t;
            int i = trip[b * 3 + 0], j = trip[b * 3 + 1], k = trip[b * 3 + 2];
            unsigned ok = (i >= 0 && j >= 0 && k >= 0 && valid[b] > 0) ? 1u : 0u;
            unsigned oi = 3u * (unsigned)min(max(i, 0), 4);
            unsigned oj = 3u * (unsigned)min(max(j, 0), 4);
            unsigned ov = 3u * (unsigned)min(max(k, 0), 4);
            unsigned e = oi | (oj << 4) | (ov << 8) | (ok << 12);
            w[t >> 1] |= e << ((t & 1) * 16);
        }
        sTbl[tid][0] = w[0]; sTbl[tid][1] = w[1];
        sTbl[tid][2] = w[2]; sTbl[tid][3] = w[3];
    }
    __syncthreads();

    const int row0 = blockIdx.x * 256;
    int rows = n - row0;
    if (rows > 256) rows = 256;
    const int cnt = rows * 15;
    const int cnt4 = cnt >> 2;
    const size_t base = (size_t)row0 * 15;
    const float4* gt = (const float4*)(y_true + base);
    const float4* gp = (const float4*)(y_pred + base);
    const float4* gm = (const float4*)(mask + base);
    float4* sT4 = (float4*)sT;
    float4* sP4 = (float4*)sP;

    // Async direct-to-LDS staging of T/P: wave-uniform LDS base + lane*16B.
    for (int ib = wv * 64; ib + 64 <= cnt4; ib += 256) {
        __builtin_amdgcn_global_load_lds(AS1U(gt + ib + lane), AS3U(sT4 + ib), 16, 0, 0);
        __builtin_amdgcn_global_load_lds(AS1U(gp + ib + lane), AS3U(sP4 + ib), 16, 0, 0);
    }
    // Tail (last block only): regular path.
    for (int i = (cnt4 & ~63) + tid; i < cnt4; i += 256) { sT4[i] = gt[i]; sP4[i] = gp[i]; }
    for (int i = (cnt4 << 2) + tid; i < cnt; i += 256) {
        sT[i] = y_true[base + i];
        sP[i] = y_pred[base + i];
    }

    // Mask -> bits (overlaps the in-flight direct-to-LDS loads). Div-free.
    for (int i = tid; i < cnt4; i += 256) {
        float4 m4 = gm[i];
        unsigned b0 = (m4.x > 0.f ? 1u : 0u) | (m4.y > 0.f ? 2u : 0u) |
                      (m4.z > 0.f ? 4u : 0u) | (m4.w > 0.f ? 8u : 0u);
        if (b0) {
            int e = i << 2;
            unsigned long long v = (unsigned long long)b0 << (e & 31);
            atomicOr(&sBits[e >> 5], (unsigned)v);
            unsigned hi = (unsigned)(v >> 32);
            if (hi) atomicOr(&sBits[(e >> 5) + 1], hi);
        }
    }
    for (int i = (cnt4 << 2) + tid; i < cnt; i += 256) {
        if (mask[base + i] > 0.f) atomicOr(&sBits[i >> 5], 1u << (i & 31));
    }
    __syncthreads();

    float result = 0.0f;
    const int row = row0 + tid;
    if (row < n) {
        const float* st = sT + tid * 15;  // stride 15 dwords (odd) -> benign banking
        const float* sp = sP + tid * 15;
        const int bb = tid * 15;
        unsigned long long mw =
            ((unsigned long long)sBits[(bb >> 5) + 1] << 32) | sBits[bb >> 5];
        const unsigned mrow = (unsigned)((mw >> (bb & 31)) & 0x7fffu);

        // ---- atom MSE (mask is binary -> bit test is exact) ----
        float num_a = 0.f, den_a = 0.f;
        unsigned avm2 = 0u;  // validity bit at position 3*a (offset-indexed)
#pragma unroll
        for (int a = 0; a < 5; a++) {
            unsigned mb = (mrow >> (3 * a)) & 7u;
            float d0 = st[3 * a + 0] - sp[3 * a + 0];
            float d1 = st[3 * a + 1] - sp[3 * a + 1];
            float d2 = st[3 * a + 2] - sp[3 * a + 2];
            float se = (mb & 1u ? d0 * d0 : 0.f) + (mb & 2u ? d1 * d1 : 0.f) +
                       (mb & 4u ? d2 * d2 : 0.f);
            if (mb) { num_a += se; den_a += 1.f; avm2 |= 1u << (3 * a); }
        }
        result = num_a / (den_a + EPSV);

        // ---- angle part ----
        float2 gb = *(const float2*)(xin + (size_t)row * 38 + 36);
        float beadf = isfinite(gb.x) ? gb.x : 0.f;
        float gatef = isfinite(gb.y) ? gb.y : 0.f;
        gatef = fminf(fmaxf(gatef, -1e6f), 1e6f);
        beadf = fminf(fmaxf(beadf, -1e6f), 1e6f);
        int res_id = min(max((int)rintf(gatef) - 1, 0), NEXP - 1);
        int bead_id = min(max((int)rintf(beadf), 0), NBEAD - 1);
        int combo = res_id * NBEAD + bead_id;
        unsigned tw0 = sTbl[combo][0], tw1 = sTbl[combo][1];
        unsigned tw2 = sTbl[combo][2], tw3 = sTbl[combo][3];

        float num_g = 0.f, den_g = 0.f;
#pragma unroll
        for (int t = 0; t < 8; t++) {
            unsigned wrd = (t < 2) ? tw0 : (t < 4) ? tw1 : (t < 6) ? tw2 : tw3;
            unsigned e = (wrd >> ((t & 1) * 16)) & 0xffffu;
            int oi = e & 15, oj = (e >> 4) & 15, ov = (e >> 8) & 15;
            bool wok = ((e >> 12) & 1u) != 0u;

            // dynamic LDS gathers replace 6 x cndmask-select chains
            float tix = st[oi], tiy = st[oi + 1], tiz = st[oi + 2];
            float tjx = st[oj], tjy = st[oj + 1], tjz = st[oj + 2];
            float tkx = st[ov], tky = st[ov + 1], tkz = st[ov + 2];
            float pix = sp[oi], piy = sp[oi + 1], piz = sp[oi + 2];
            float pjx = sp[oj], pjy = sp[oj + 1], pjz = sp[oj + 2];
            float pkx = sp[ov], pky = sp[ov + 1], pkz = sp[ov + 2];

            float v1tx = tix - tjx, v1ty = tiy - tjy, v1tz = tiz - tjz;
            float v2tx = tkx - tjx, v2ty = tky - tjy, v2tz = tkz - tjz;
            float v1px = pix - pjx, v1py = piy - pjy, v1pz = piz - pjz;
            float v2px = pkx - pjx, v2py = pky - pjy, v2pz = pkz - pjz;

            float l1t = fmaf(v1tx, v1tx, fmaf(v1ty, v1ty, v1tz * v1tz));
            float l2t = fmaf(v2tx, v2tx, fmaf(v2ty, v2ty, v2tz * v2tz));
            float l1p = fmaf(v1px, v1px, fmaf(v1py, v1py, v1pz * v1pz));
            float l2p = fmaf(v2px, v2px, fmaf(v2py, v2py, v2pz * v2pz));

            bool okv = wok && ((avm2 >> oi) & 1) && ((avm2 >> oj) & 1) &&
                       ((avm2 >> ov) & 1) && (l1t > ML2) && (l2t > ML2) &&
                       (l1p > ML2) && (l2p > ML2);

            float rt = __builtin_amdgcn_rsqf(fmaxf(l1t, ML2) * fmaxf(l2t, ML2));
            float rp = __builtin_amdgcn_rsqf(fmaxf(l1p, ML2) * fmaxf(l2p, ML2));

            float dott = fmaf(v1tx, v2tx, fmaf(v1ty, v2ty, v1tz * v2tz));
            float dotp = fmaf(v1px, v2px, fmaf(v1py, v2py, v1pz * v2pz));
            float cut = dott * rt;
            float cup = dotp * rp;
            float cost = fminf(fmaxf(cut, -1.f + 1e-6f), 1.f - 1e-6f);
            float cosp = fminf(fmaxf(cup, -1.f + 1e-6f), 1.f - 1e-6f);
            // |u1 x u2| = sqrt(1 - cos^2) with unclipped cos
            float sint = __builtin_amdgcn_sqrtf(fmaxf(fmaf(-cut, cut, 1.f), 0.f));
            float sinp = __builtin_amdgcn_sqrtf(fmaxf(fmaf(-cup, cup, 1.f), 0.f));

            float dc = cosp - cost, dsn = sinp - sint;
            if (okv) { num_g += fmaf(dc, dc, dsn * dsn); den_g += 1.f; }
        }
        result += num_g / (den_g + EPSV);
    }

    // ---- block reduction (red aliases sBits; barrier protects reuse) ----
    __syncthreads();
#pragma unroll
    for (int off = 32; off > 0; off >>= 1)
        result += __shfl_down(result, off, 64);
    float* red = (float*)sBits;
    if (lane == 0) red[wv] = result;
    __syncthreads();
    // Contention-free: one plain store per block to a distinct address.
    if (tid == 0) partial[blockIdx.x] = red[0] + red[1] + red[2] + red[3];
}

__global__ __launch_bounds__(256) void reduce_kernel(const float* __restrict__ partial,
                                                     float* __restrict__ out, int nblocks,
                                                     float inv_n) {
    __shared__ float red[4];
    float s = 0.f;
    for (int i = threadIdx.x; i < nblocks; i += 256) s += partial[i];
#pragma unroll
    for (int off = 32; off > 0; off >>= 1) s += __shfl_down(s, off, 64);
    int lane = threadIdx.x & 63, wv = threadIdx.x >> 6;
    if (lane == 0) red[wv] = s;
    __syncthreads();
    if (threadIdx.x == 0) out[0] = (red[0] + red[1] + red[2] + red[3]) * inv_n;
}

extern "C" void kernel_launch(void* const* d_in, const int* in_sizes, int n_in,
                              void* d_out, int out_size, void* d_ws, size_t ws_size,
                              hipStream_t stream) {
    const float* x = (const float*)d_in[0];
    const float* y_true = (const float*)d_in[1];
    const float* y_pred = (const float*)d_in[2];
    const float* mask = (const float*)d_in[3];
    const int* trip = (const int*)d_in[4];
    const int* valid = (const int*)d_in[5];
    float* out = (float*)d_out;
    float* partial = (float*)d_ws;

    const int n = in_sizes[1] / 15;  // N rows (y_true is N x 15)
    const int blocks = (n + 255) / 256;

    loss_kernel<<<blocks, 256, 0, stream>>>(x, y_true, y_pred, mask, trip, valid, partial, n);
    reduce_kernel<<<1, 256, 0, stream>>>(partial, out, blocks, 1.0f / (float)n);
}